// Round 10
// baseline (644.071 us; speedup 1.0000x reference)
//
#include <hip/hip_runtime.h>

#define HID 128
#define TPB 256
#define NBLOCKS 768   // 256 CU x 3 blocks/CU (40KB LDS, ~160 VGPR -> 3 waves/EU)

typedef __attribute__((ext_vector_type(8))) short short8v;   // 8 bf16 = 4 VGPR (MFMA A/B frag)
typedef __attribute__((ext_vector_type(16))) float f32x16;   // MFMA C/D frag

__device__ __forceinline__ float bf2f(unsigned short u) {
    return __uint_as_float(((unsigned int)u) << 16);
}
__device__ __forceinline__ unsigned short f2bf(float f) {
    unsigned int u = __float_as_uint(f);
    return (unsigned short)((u + 0x7FFFu + ((u >> 16) & 1u)) >> 16);  // RNE
}
__device__ __forceinline__ float silu(float x) {
    return x / (1.0f + __expf(-x));
}
// h tiles in LDS: [64 atoms][128 feats] bf16, XOR swizzle: 16B granule index
// XORed with row&15 (R6: bank conflicts 1.0e7 -> 2.2e6, ~1% of LDS cycles).
__device__ __forceinline__ int swz(int m, int k) {
    return (m * HID + k) ^ ((m & 15) << 3);
}

// R6 lesson: short8v A0[8] stays an alloca (scratch!) even with #pragma unroll
// -> 617MB HBM FETCH of spill traffic, VGPR=84. Named variables never go
// through alloca. Preload + MFMA steps are macro-expanded over named regs.
#define LOADW(dst, off0) { \
    short8v a_; \
    _Pragma("unroll") \
    for (int i = 0; i < 8; ++i) a_[i] = (short)f2bf(W_h[(off0) + i * HID]); \
    dst = a_; }

#define MSTEP(Areg, s, HSRC) { \
    const int k0_ = 16 * (s) + 8 * hi; \
    const short8v Ba_ = *reinterpret_cast<const short8v*>(&HSRC[swz(lm, k0_)]); \
    const short8v Bb_ = *reinterpret_cast<const short8v*>(&HSRC[swz(32 + lm, k0_)]); \
    acc0 = __builtin_amdgcn_mfma_f32_32x32x16_bf16(Areg, Ba_, acc0, 0, 0, 0); \
    acc1 = __builtin_amdgcn_mfma_f32_32x32x16_bf16(Areg, Bb_, acc1, 0, 0, 0); }

__global__ __launch_bounds__(TPB, 3) void mlp_kernel(
    const float* __restrict__ pos, const int* __restrict__ anum,
    const int* __restrict__ batch,
    const float* __restrict__ W_in, const float* __restrict__ b_in,
    const float* __restrict__ W_h, const float* __restrict__ b_h,
    const float* __restrict__ W_e, const float* __restrict__ b_e,
    const float* __restrict__ W_s,
    float* __restrict__ out_energies,   // d_out base (energies at offset 0)
    float* __restrict__ ws6,            // 6 stress partial sums
    int nAtoms)
{
    __shared__ unsigned short h1[64 * HID];   // 16 KB
    __shared__ unsigned short h2[64 * HID];   // 16 KB
    __shared__ float featsL[64][4];           // 1 KB
    __shared__ float bh0L[HID], bh1L[HID], WeL[HID];
    __shared__ float WsL[HID][8];             // 4 KB (rows 32B-aligned)
    __shared__ float ered[4 * 64];            // 1 KB

    const int t    = threadIdx.x;
    const int lane = t & 63;
    const int w    = t >> 6;          // wave 0..3, owns feature block Fw..Fw+31
    const int hi   = lane >> 5;       // lane half (selects k-slice of fragments)
    const int lm   = lane & 31;       // MFMA row/col index
    const int Fw   = 32 * w;

    // ---- stage small constant tables (once per block) ----
    if (t < HID) {
        bh0L[t] = b_h[t];
        bh1L[t] = b_h[HID + t];
        WeL[t]  = W_e[t];
        #pragma unroll
        for (int c = 0; c < 6; ++c) WsL[t][c] = W_s[t * 6 + c];
    }

    // ---- per-thread h1 (input layer) weights: feature j ----
    const int j    = t & 127;
    const int slab = t >> 7;          // atoms [32*slab, 32*slab+32)
    const float wi0 = W_in[0 * HID + j], wi1 = W_in[1 * HID + j];
    const float wi2 = W_in[2 * HID + j], wi3 = W_in[3 * HID + j];
    const float bin = b_in[j];
    const float be  = b_e[0];

    // ---- preload W^T A-fragments, both layers, NAMED registers (64 VGPR) ----
    // A-frag (32x32x16): lane holds A[row = lm][k = 16s + 8*hi + i], i=0..7
    short8v A00, A01, A02, A03, A04, A05, A06, A07;
    short8v A10, A11, A12, A13, A14, A15, A16, A17;
    {
        const int fc = Fw + lm;
        const int o0 = 8 * hi * HID + fc;          // layer 0, s=0 base
        const int o1 = HID * HID + o0;             // layer 1, s=0 base
        LOADW(A00, o0 +  0 * 16 * HID);  LOADW(A01, o0 +  1 * 16 * HID);
        LOADW(A02, o0 +  2 * 16 * HID);  LOADW(A03, o0 +  3 * 16 * HID);
        LOADW(A04, o0 +  4 * 16 * HID);  LOADW(A05, o0 +  5 * 16 * HID);
        LOADW(A06, o0 +  6 * 16 * HID);  LOADW(A07, o0 +  7 * 16 * HID);
        LOADW(A10, o1 +  0 * 16 * HID);  LOADW(A11, o1 +  1 * 16 * HID);
        LOADW(A12, o1 +  2 * 16 * HID);  LOADW(A13, o1 +  3 * 16 * HID);
        LOADW(A14, o1 +  4 * 16 * HID);  LOADW(A15, o1 +  5 * 16 * HID);
        LOADW(A16, o1 +  6 * 16 * HID);  LOADW(A17, o1 +  7 * 16 * HID);
    }

    float sacc[6] = {0.f, 0.f, 0.f, 0.f, 0.f, 0.f};

    const int nTiles = (nAtoms + 63) >> 6;
    for (int tile = blockIdx.x; tile < nTiles; tile += gridDim.x) {
        const int base = tile << 6;
        __syncthreads();   // protect prev-tile LDS readers before rewrite

        // ---- stage atom features [64][4] ----
        if (t < 192) {
            int idx = base * 3 + t;
            const int gmax = nAtoms * 3 - 1;
            if (idx > gmax) idx = gmax;
            featsL[t / 3][t % 3] = pos[idx];
        } else if (t < 256) {
            const int a = t - 192;
            int ga = base + a; if (ga >= nAtoms) ga = nAtoms - 1;
            featsL[a][3] = (float)anum[ga];
        }
        __syncthreads();

        // ---- input layer: h1[a][j] = silu(feats @ W_in + b_in) ----
        #pragma unroll 4
        for (int ai = 0; ai < 32; ++ai) {
            const int a = 32 * slab + ai;
            const float4 ft = *reinterpret_cast<const float4*>(&featsL[a][0]);
            const float z = fmaf(wi0, ft.x, fmaf(wi1, ft.y,
                            fmaf(wi2, ft.z, fmaf(wi3, ft.w, bin))));
            h1[swz(a, j)] = f2bf(silu(z));
        }
        __syncthreads();

        // ---- layer 0 MFMA: z2[f][m] = W0^T · h1^T + b0 ----
        f32x16 acc0, acc1;
        #pragma unroll
        for (int r = 0; r < 16; ++r) {
            const float b = bh0L[Fw + (r & 3) + 8 * (r >> 2) + 4 * hi];
            acc0[r] = b; acc1[r] = b;
        }
        MSTEP(A00, 0, h1)  MSTEP(A01, 1, h1)  MSTEP(A02, 2, h1)  MSTEP(A03, 3, h1)
        MSTEP(A04, 4, h1)  MSTEP(A05, 5, h1)  MSTEP(A06, 6, h1)  MSTEP(A07, 7, h1)

        // silu -> bf16 -> h2 (C/D reg quads are 4 consecutive f rows -> ushort4 stores)
        #pragma unroll
        for (int g = 0; g < 4; ++g) {
            const int f0 = Fw + 8 * g + 4 * hi;
            ushort4 pa, pb;
            pa.x = f2bf(silu(acc0[4*g+0])); pa.y = f2bf(silu(acc0[4*g+1]));
            pa.z = f2bf(silu(acc0[4*g+2])); pa.w = f2bf(silu(acc0[4*g+3]));
            pb.x = f2bf(silu(acc1[4*g+0])); pb.y = f2bf(silu(acc1[4*g+1]));
            pb.z = f2bf(silu(acc1[4*g+2])); pb.w = f2bf(silu(acc1[4*g+3]));
            *reinterpret_cast<ushort4*>(&h2[swz(lm,      f0)]) = pa;
            *reinterpret_cast<ushort4*>(&h2[swz(32 + lm, f0)]) = pb;
        }
        __syncthreads();

        // ---- layer 1 MFMA: z3[f][m] = W1^T · h2^T + b1 ----
        #pragma unroll
        for (int r = 0; r < 16; ++r) {
            const float b = bh1L[Fw + (r & 3) + 8 * (r >> 2) + 4 * hi];
            acc0[r] = b; acc1[r] = b;
        }
        MSTEP(A10, 0, h2)  MSTEP(A11, 1, h2)  MSTEP(A12, 2, h2)  MSTEP(A13, 3, h2)
        MSTEP(A14, 4, h2)  MSTEP(A15, 5, h2)  MSTEP(A16, 6, h2)  MSTEP(A17, 7, h2)

        // ---- epilogue: h3 = silu(z3); energies dot W_e; stress dot W_s ----
        const bool v0 = (base + lm)      < nAtoms;
        const bool v1 = (base + 32 + lm) < nAtoms;
        float e0 = 0.f, e1 = 0.f;
        #pragma unroll
        for (int r = 0; r < 16; ++r) {
            const int f = Fw + (r & 3) + 8 * (r >> 2) + 4 * hi;
            const float h3a = silu(acc0[r]);
            const float h3b = silu(acc1[r]);
            const float we = WeL[f];
            e0 = fmaf(h3a, we, e0);
            e1 = fmaf(h3b, we, e1);
            const float hs = (v0 ? h3a : 0.f) + (v1 ? h3b : 0.f);
            #pragma unroll
            for (int c = 0; c < 6; ++c) sacc[c] = fmaf(hs, WsL[f][c], sacc[c]);
        }
        // combine lane halves: each lane then holds full e for its atom column
        e0 += __shfl_xor(e0, 32);
        e1 += __shfl_xor(e1, 32);
        const float ev = (lane < 32) ? e0 : e1;   // lane l <-> atom base+l
        ered[w * 64 + lane] = ev;
        __syncthreads();

        // ---- wave 0: sum feature slices, add b_e, segmented-scan, atomic ----
        if (w == 0) {
            float e = ered[lane] + ered[64 + lane] + ered[128 + lane] + ered[192 + lane] + be;
            const int ga = base + lane;
            int key = (ga < nAtoms) ? batch[ga] : -1;
            if (key < 0) e = 0.f;
            #pragma unroll
            for (int d = 1; d < 64; d <<= 1) {
                const float eo = __shfl_down(e, d);
                const int   ko = __shfl_down(key, d);
                const bool valid = ((lane + d) < 64) && (ko == key);
                e += valid ? eo : 0.f;
            }
            const int kprev = __shfl_up(key, 1);
            const bool head = (lane == 0) || (kprev != key);
            if (head && key >= 0) atomicAdd(&out_energies[key], e);
        }
    }

    // ---- stress: reduce 6 per-lane partials across wave, one atomic each ----
    #pragma unroll
    for (int c = 0; c < 6; ++c) {
        float v = sacc[c];
        #pragma unroll
        for (int d = 1; d < 64; d <<= 1) v += __shfl_xor(v, d);
        if (lane == 0) atomicAdd(&ws6[c], v);
    }
}

__global__ void stress_kernel(const float* __restrict__ ws6,
                              const float* __restrict__ b_s,
                              float* __restrict__ out_stress, float invN)
{
    const int c = threadIdx.x;
    if (c < 6) out_stress[c] = fmaf(ws6[c], invN, b_s[c]);
}

extern "C" void kernel_launch(void* const* d_in, const int* in_sizes, int n_in,
                              void* d_out, int out_size, void* d_ws, size_t ws_size,
                              hipStream_t stream) {
    const float* pos  = (const float*)d_in[0];
    const int*   anum = (const int*)d_in[1];
    const int*   batch= (const int*)d_in[2];
    const float* W_in = (const float*)d_in[3];
    const float* b_in = (const float*)d_in[4];
    const float* W_h  = (const float*)d_in[5];
    const float* b_h  = (const float*)d_in[6];
    const float* W_e  = (const float*)d_in[7];
    const float* b_e  = (const float*)d_in[8];
    const float* W_s  = (const float*)d_in[9];
    const float* b_s  = (const float*)d_in[10];

    float* out = (float*)d_out;
    const int nAtoms  = in_sizes[2];                 // batch[] length == N
    const int nStruct = out_size - 3 * nAtoms - 6;   // energies | forces | stress
    float* ws6 = (float*)d_ws;

    hipMemsetAsync(d_out, 0, (size_t)out_size * sizeof(float), stream);
    hipMemsetAsync(d_ws, 0, 32, stream);

    mlp_kernel<<<NBLOCKS, TPB, 0, stream>>>(pos, anum, batch, W_in, b_in, W_h, b_h,
                                            W_e, b_e, W_s, out, ws6, nAtoms);
    stress_kernel<<<1, 64, 0, stream>>>(ws6, b_s,
                                        out + (size_t)nStruct + 3 * (size_t)nAtoms,
                                        1.0f / (float)nAtoms);
}

// Round 11
// 511.042 us; speedup vs baseline: 1.2603x; 1.2603x over previous
//
#include <hip/hip_runtime.h>

#define HID 128
#define TPB 256
#define NBLOCKS 768   // 256 CU x 3 blocks/CU (40KB LDS)

typedef __attribute__((ext_vector_type(8))) short short8v;   // 8 bf16 = 4 VGPR (MFMA A/B frag)
typedef __attribute__((ext_vector_type(16))) float f32x16;   // MFMA C/D frag

__device__ __forceinline__ float bf2f(unsigned short u) {
    return __uint_as_float(((unsigned int)u) << 16);
}
__device__ __forceinline__ unsigned short f2bf(float f) {
    unsigned int u = __float_as_uint(f);
    return (unsigned short)((u + 0x7FFFu + ((u >> 16) & 1u)) >> 16);  // RNE
}
__device__ __forceinline__ float silu(float x) {
    return x / (1.0f + __expf(-x));
}
// h tiles in LDS: [64 atoms][128 feats] bf16, XOR swizzle: 16B granule index
// XORed with row&15 (R6: bank conflicts 1.0e7 -> 2.2e6, ~1% of LDS cycles).
__device__ __forceinline__ int swz(int m, int k) {
    return (m * HID + k) ^ ((m & 15) << 3);
}

// R10 lesson: VGPR=84 across 3 source variants => allocator BUDGET spill, not
// alloca. 84 ~= 512/6: backend targeted ~6 waves/EU under launch_bounds(256,3)
// and spilled the ~148-reg working set to scratch (WRITE 72MB one-time spill,
// FETCH ~600MB of per-tile re-reads; scratch footprint >> L2 => HBM).
// Single change this round: min waves/EU 3 -> 2 (VGPR budget 256 >= need).
#define LOADW(dst, off0) { \
    short8v a_; \
    _Pragma("unroll") \
    for (int i = 0; i < 8; ++i) a_[i] = (short)f2bf(W_h[(off0) + i * HID]); \
    dst = a_; }

#define MSTEP(Areg, s, HSRC) { \
    const int k0_ = 16 * (s) + 8 * hi; \
    const short8v Ba_ = *reinterpret_cast<const short8v*>(&HSRC[swz(lm, k0_)]); \
    const short8v Bb_ = *reinterpret_cast<const short8v*>(&HSRC[swz(32 + lm, k0_)]); \
    acc0 = __builtin_amdgcn_mfma_f32_32x32x16_bf16(Areg, Ba_, acc0, 0, 0, 0); \
    acc1 = __builtin_amdgcn_mfma_f32_32x32x16_bf16(Areg, Bb_, acc1, 0, 0, 0); }

__global__ __launch_bounds__(TPB, 2) void mlp_kernel(
    const float* __restrict__ pos, const int* __restrict__ anum,
    const int* __restrict__ batch,
    const float* __restrict__ W_in, const float* __restrict__ b_in,
    const float* __restrict__ W_h, const float* __restrict__ b_h,
    const float* __restrict__ W_e, const float* __restrict__ b_e,
    const float* __restrict__ W_s,
    float* __restrict__ out_energies,   // d_out base (energies at offset 0)
    float* __restrict__ ws6,            // 6 stress partial sums
    int nAtoms)
{
    __shared__ unsigned short h1[64 * HID];   // 16 KB
    __shared__ unsigned short h2[64 * HID];   // 16 KB
    __shared__ float featsL[64][4];           // 1 KB
    __shared__ float bh0L[HID], bh1L[HID], WeL[HID];
    __shared__ float WsL[HID][8];             // 4 KB (rows 32B-aligned)
    __shared__ float ered[4 * 64];            // 1 KB

    const int t    = threadIdx.x;
    const int lane = t & 63;
    const int w    = t >> 6;          // wave 0..3, owns feature block Fw..Fw+31
    const int hi   = lane >> 5;       // lane half (selects k-slice of fragments)
    const int lm   = lane & 31;       // MFMA row/col index
    const int Fw   = 32 * w;

    // ---- stage small constant tables (once per block) ----
    if (t < HID) {
        bh0L[t] = b_h[t];
        bh1L[t] = b_h[HID + t];
        WeL[t]  = W_e[t];
        #pragma unroll
        for (int c = 0; c < 6; ++c) WsL[t][c] = W_s[t * 6 + c];
    }

    // ---- per-thread h1 (input layer) weights: feature j ----
    const int j    = t & 127;
    const int slab = t >> 7;          // atoms [32*slab, 32*slab+32)
    const float wi0 = W_in[0 * HID + j], wi1 = W_in[1 * HID + j];
    const float wi2 = W_in[2 * HID + j], wi3 = W_in[3 * HID + j];
    const float bin = b_in[j];
    const float be  = b_e[0];

    // ---- preload W^T A-fragments, both layers, NAMED registers (64 VGPR) ----
    // A-frag (32x32x16): lane holds A[row = lm][k = 16s + 8*hi + i], i=0..7
    short8v A00, A01, A02, A03, A04, A05, A06, A07;
    short8v A10, A11, A12, A13, A14, A15, A16, A17;
    {
        const int fc = Fw + lm;
        const int o0 = 8 * hi * HID + fc;          // layer 0, s=0 base
        const int o1 = HID * HID + o0;             // layer 1, s=0 base
        LOADW(A00, o0 +  0 * 16 * HID);  LOADW(A01, o0 +  1 * 16 * HID);
        LOADW(A02, o0 +  2 * 16 * HID);  LOADW(A03, o0 +  3 * 16 * HID);
        LOADW(A04, o0 +  4 * 16 * HID);  LOADW(A05, o0 +  5 * 16 * HID);
        LOADW(A06, o0 +  6 * 16 * HID);  LOADW(A07, o0 +  7 * 16 * HID);
        LOADW(A10, o1 +  0 * 16 * HID);  LOADW(A11, o1 +  1 * 16 * HID);
        LOADW(A12, o1 +  2 * 16 * HID);  LOADW(A13, o1 +  3 * 16 * HID);
        LOADW(A14, o1 +  4 * 16 * HID);  LOADW(A15, o1 +  5 * 16 * HID);
        LOADW(A16, o1 +  6 * 16 * HID);  LOADW(A17, o1 +  7 * 16 * HID);
    }

    float sacc[6] = {0.f, 0.f, 0.f, 0.f, 0.f, 0.f};

    const int nTiles = (nAtoms + 63) >> 6;
    for (int tile = blockIdx.x; tile < nTiles; tile += gridDim.x) {
        const int base = tile << 6;
        __syncthreads();   // protect prev-tile LDS readers before rewrite

        // ---- stage atom features [64][4] ----
        if (t < 192) {
            int idx = base * 3 + t;
            const int gmax = nAtoms * 3 - 1;
            if (idx > gmax) idx = gmax;
            featsL[t / 3][t % 3] = pos[idx];
        } else if (t < 256) {
            const int a = t - 192;
            int ga = base + a; if (ga >= nAtoms) ga = nAtoms - 1;
            featsL[a][3] = (float)anum[ga];
        }
        __syncthreads();

        // ---- input layer: h1[a][j] = silu(feats @ W_in + b_in) ----
        #pragma unroll 4
        for (int ai = 0; ai < 32; ++ai) {
            const int a = 32 * slab + ai;
            const float4 ft = *reinterpret_cast<const float4*>(&featsL[a][0]);
            const float z = fmaf(wi0, ft.x, fmaf(wi1, ft.y,
                            fmaf(wi2, ft.z, fmaf(wi3, ft.w, bin))));
            h1[swz(a, j)] = f2bf(silu(z));
        }
        __syncthreads();

        // ---- layer 0 MFMA: z2[f][m] = W0^T · h1^T + b0 ----
        f32x16 acc0, acc1;
        #pragma unroll
        for (int r = 0; r < 16; ++r) {
            const float b = bh0L[Fw + (r & 3) + 8 * (r >> 2) + 4 * hi];
            acc0[r] = b; acc1[r] = b;
        }
        MSTEP(A00, 0, h1)  MSTEP(A01, 1, h1)  MSTEP(A02, 2, h1)  MSTEP(A03, 3, h1)
        MSTEP(A04, 4, h1)  MSTEP(A05, 5, h1)  MSTEP(A06, 6, h1)  MSTEP(A07, 7, h1)

        // silu -> bf16 -> h2 (C/D reg quads are 4 consecutive f rows -> ushort4 stores)
        #pragma unroll
        for (int g = 0; g < 4; ++g) {
            const int f0 = Fw + 8 * g + 4 * hi;
            ushort4 pa, pb;
            pa.x = f2bf(silu(acc0[4*g+0])); pa.y = f2bf(silu(acc0[4*g+1]));
            pa.z = f2bf(silu(acc0[4*g+2])); pa.w = f2bf(silu(acc0[4*g+3]));
            pb.x = f2bf(silu(acc1[4*g+0])); pb.y = f2bf(silu(acc1[4*g+1]));
            pb.z = f2bf(silu(acc1[4*g+2])); pb.w = f2bf(silu(acc1[4*g+3]));
            *reinterpret_cast<ushort4*>(&h2[swz(lm,      f0)]) = pa;
            *reinterpret_cast<ushort4*>(&h2[swz(32 + lm, f0)]) = pb;
        }
        __syncthreads();

        // ---- layer 1 MFMA: z3[f][m] = W1^T · h2^T + b1 ----
        #pragma unroll
        for (int r = 0; r < 16; ++r) {
            const float b = bh1L[Fw + (r & 3) + 8 * (r >> 2) + 4 * hi];
            acc0[r] = b; acc1[r] = b;
        }
        MSTEP(A10, 0, h2)  MSTEP(A11, 1, h2)  MSTEP(A12, 2, h2)  MSTEP(A13, 3, h2)
        MSTEP(A14, 4, h2)  MSTEP(A15, 5, h2)  MSTEP(A16, 6, h2)  MSTEP(A17, 7, h2)

        // ---- epilogue: h3 = silu(z3); energies dot W_e; stress dot W_s ----
        const bool v0 = (base + lm)      < nAtoms;
        const bool v1 = (base + 32 + lm) < nAtoms;
        float e0 = 0.f, e1 = 0.f;
        #pragma unroll
        for (int r = 0; r < 16; ++r) {
            const int f = Fw + (r & 3) + 8 * (r >> 2) + 4 * hi;
            const float h3a = silu(acc0[r]);
            const float h3b = silu(acc1[r]);
            const float we = WeL[f];
            e0 = fmaf(h3a, we, e0);
            e1 = fmaf(h3b, we, e1);
            const float hs = (v0 ? h3a : 0.f) + (v1 ? h3b : 0.f);
            #pragma unroll
            for (int c = 0; c < 6; ++c) sacc[c] = fmaf(hs, WsL[f][c], sacc[c]);
        }
        // combine lane halves: each lane then holds full e for its atom column
        e0 += __shfl_xor(e0, 32);
        e1 += __shfl_xor(e1, 32);
        const float ev = (lane < 32) ? e0 : e1;   // lane l <-> atom base+l
        ered[w * 64 + lane] = ev;
        __syncthreads();

        // ---- wave 0: sum feature slices, add b_e, segmented-scan, atomic ----
        if (w == 0) {
            float e = ered[lane] + ered[64 + lane] + ered[128 + lane] + ered[192 + lane] + be;
            const int ga = base + lane;
            int key = (ga < nAtoms) ? batch[ga] : -1;
            if (key < 0) e = 0.f;
            #pragma unroll
            for (int d = 1; d < 64; d <<= 1) {
                const float eo = __shfl_down(e, d);
                const int   ko = __shfl_down(key, d);
                const bool valid = ((lane + d) < 64) && (ko == key);
                e += valid ? eo : 0.f;
            }
            const int kprev = __shfl_up(key, 1);
            const bool head = (lane == 0) || (kprev != key);
            if (head && key >= 0) atomicAdd(&out_energies[key], e);
        }
    }

    // ---- stress: reduce 6 per-lane partials across wave, one atomic each ----
    #pragma unroll
    for (int c = 0; c < 6; ++c) {
        float v = sacc[c];
        #pragma unroll
        for (int d = 1; d < 64; d <<= 1) v += __shfl_xor(v, d);
        if (lane == 0) atomicAdd(&ws6[c], v);
    }
}

__global__ void stress_kernel(const float* __restrict__ ws6,
                              const float* __restrict__ b_s,
                              float* __restrict__ out_stress, float invN)
{
    const int c = threadIdx.x;
    if (c < 6) out_stress[c] = fmaf(ws6[c], invN, b_s[c]);
}

extern "C" void kernel_launch(void* const* d_in, const int* in_sizes, int n_in,
                              void* d_out, int out_size, void* d_ws, size_t ws_size,
                              hipStream_t stream) {
    const float* pos  = (const float*)d_in[0];
    const int*   anum = (const int*)d_in[1];
    const int*   batch= (const int*)d_in[2];
    const float* W_in = (const float*)d_in[3];
    const float* b_in = (const float*)d_in[4];
    const float* W_h  = (const float*)d_in[5];
    const float* b_h  = (const float*)d_in[6];
    const float* W_e  = (const float*)d_in[7];
    const float* b_e  = (const float*)d_in[8];
    const float* W_s  = (const float*)d_in[9];
    const float* b_s  = (const float*)d_in[10];

    float* out = (float*)d_out;
    const int nAtoms  = in_sizes[2];                 // batch[] length == N
    const int nStruct = out_size - 3 * nAtoms - 6;   // energies | forces | stress
    float* ws6 = (float*)d_ws;

    hipMemsetAsync(d_out, 0, (size_t)out_size * sizeof(float), stream);
    hipMemsetAsync(d_ws, 0, 32, stream);

    mlp_kernel<<<NBLOCKS, TPB, 0, stream>>>(pos, anum, batch, W_in, b_in, W_h, b_h,
                                            W_e, b_e, W_s, out, ws6, nAtoms);
    stress_kernel<<<1, 64, 0, stream>>>(ws6, b_s,
                                        out + (size_t)nStruct + 3 * (size_t)nAtoms,
                                        1.0f / (float)nAtoms);
}

// Round 15
// 442.447 us; speedup vs baseline: 1.4557x; 1.1550x over previous
//
#include <hip/hip_runtime.h>

#define HID 128
#define TPB 256
#define NBLOCKS 768

typedef __attribute__((ext_vector_type(8))) short short8v;   // 8 bf16 = 4 VGPR
typedef __attribute__((ext_vector_type(16))) float f32x16;   // MFMA C/D frag

__device__ __forceinline__ unsigned short f2bf(float f) {
    unsigned int u = __float_as_uint(f);
    return (unsigned short)((u + 0x7FFFu + ((u >> 16) & 1u)) >> 16);  // RNE
}
__device__ __forceinline__ float silu(float x) {
    return x / (1.0f + __expf(-x));
}
// h tiles in LDS: [64 atoms][128 feats] bf16, 16-row XOR swizzle (R6-verified)
__device__ __forceinline__ int swz(int m, int k) {
    return (m * HID + k) ^ ((m & 15) << 3);
}

#define LOADW(dst, off0) { \
    short8v a_; \
    _Pragma("unroll") \
    for (int i = 0; i < 8; ++i) a_[i] = (short)f2bf(W_h[(off0) + i * HID]); \
    dst = a_; }

#define MSTEP(Areg, s, HSRC) { \
    const int k0_ = 16 * (s) + 8 * hi; \
    const short8v Ba_ = *reinterpret_cast<const short8v*>(&HSRC[swz(lm, k0_)]); \
    const short8v Bb_ = *reinterpret_cast<const short8v*>(&HSRC[swz(32 + lm, k0_)]); \
    acc0 = __builtin_amdgcn_mfma_f32_32x32x16_bf16(Areg, Ba_, acc0, 0, 0, 0); \
    acc1 = __builtin_amdgcn_mfma_f32_32x32x16_bf16(Areg, Bb_, acc1, 0, 0, 0); }

// C/D-frag -> LDS [atom][feat] writeback: 4 consecutive f rows per reg quad
#define PACK_STORE(DST, ACCA, ACCB) \
    _Pragma("unroll") \
    for (int g = 0; g < 4; ++g) { \
        const int f0 = Fw + 8 * g + 4 * hi; \
        ushort4 pa, pb; \
        pa.x = f2bf(silu(ACCA[4*g+0])); pa.y = f2bf(silu(ACCA[4*g+1])); \
        pa.z = f2bf(silu(ACCA[4*g+2])); pa.w = f2bf(silu(ACCA[4*g+3])); \
        pb.x = f2bf(silu(ACCB[4*g+0])); pb.y = f2bf(silu(ACCB[4*g+1])); \
        pb.z = f2bf(silu(ACCB[4*g+2])); pb.w = f2bf(silu(ACCB[4*g+3])); \
        *reinterpret_cast<ushort4*>(&DST[swz(lm,      f0)]) = pa; \
        *reinterpret_cast<ushort4*>(&DST[swz(32 + lm, f0)]) = pb; \
    }

__global__ __launch_bounds__(TPB, 2) void mlp_kernel(
    const float* __restrict__ pos, const int* __restrict__ anum,
    const int* __restrict__ batch,
    const float* __restrict__ W_in, const float* __restrict__ b_in,
    const float* __restrict__ W_h, const float* __restrict__ b_h,
    const float* __restrict__ W_e, const float* __restrict__ b_e,
    const float* __restrict__ W_s,
    float* __restrict__ out_energies,
    float* __restrict__ ws6,
    int nAtoms)
{
    __shared__ unsigned short h1[64 * HID];   // 16 KB
    __shared__ unsigned short h2[64 * HID];   // 16 KB
    __shared__ float binL[HID], bh0L[HID], bh1L[HID], WeL[HID];
    __shared__ float WsL[HID][8];             // 4 KB
    __shared__ float ered[4 * 64];            // 1 KB

    const int t    = threadIdx.x;
    const int lane = t & 63;
    const int w    = t >> 6;          // wave 0..3, feature block Fw..Fw+31
    const int hi   = lane >> 5;
    const int lm   = lane & 31;
    const int Fw   = 32 * w;

    if (t < HID) {
        binL[t] = b_in[t];
        bh0L[t] = b_h[t];
        bh1L[t] = b_h[HID + t];
        WeL[t]  = W_e[t];
        #pragma unroll
        for (int c = 0; c < 6; ++c) WsL[t][c] = W_s[t * 6 + c];
    }
    const float be = b_e[0];

    // ---- W^T A-fragments, named regs (R10/R11: budget was the spill cause) ----
    short8v A00, A01, A02, A03, A04, A05, A06, A07;
    short8v A10, A11, A12, A13, A14, A15, A16, A17;
    short8v Ain;   // input layer: A[f][k] = W_in[k][f], k<4 real, else 0
    {
        const int fc = Fw + lm;
        const int o0 = 8 * hi * HID + fc;
        const int o1 = HID * HID + o0;
        LOADW(A00, o0 +  0 * 16 * HID);  LOADW(A01, o0 +  1 * 16 * HID);
        LOADW(A02, o0 +  2 * 16 * HID);  LOADW(A03, o0 +  3 * 16 * HID);
        LOADW(A04, o0 +  4 * 16 * HID);  LOADW(A05, o0 +  5 * 16 * HID);
        LOADW(A06, o0 +  6 * 16 * HID);  LOADW(A07, o0 +  7 * 16 * HID);
        LOADW(A10, o1 +  0 * 16 * HID);  LOADW(A11, o1 +  1 * 16 * HID);
        LOADW(A12, o1 +  2 * 16 * HID);  LOADW(A13, o1 +  3 * 16 * HID);
        LOADW(A14, o1 +  4 * 16 * HID);  LOADW(A15, o1 +  5 * 16 * HID);
        LOADW(A16, o1 +  6 * 16 * HID);  LOADW(A17, o1 +  7 * 16 * HID);
        #pragma unroll
        for (int i = 0; i < 8; ++i) Ain[i] = 0;
        if (hi == 0) {
            Ain[0] = (short)f2bf(W_in[0 * HID + fc]);
            Ain[1] = (short)f2bf(W_in[1 * HID + fc]);
            Ain[2] = (short)f2bf(W_in[2 * HID + fc]);
            Ain[3] = (short)f2bf(W_in[3 * HID + fc]);
        }
    }

    f32x16 hsum;               // deferred stress accumulator (per-r h3 sums)
    #pragma unroll
    for (int r = 0; r < 16; ++r) hsum[r] = 0.f;

    const int nTiles = (nAtoms + 63) >> 6;
    for (int tile = blockIdx.x; tile < nTiles; tile += gridDim.x) {
        const int base = tile << 6;

        // ---- input layer via MFMA: feats B-frags built from global loads ----
        short8v Fa, Fb;
        #pragma unroll
        for (int i = 0; i < 8; ++i) { Fa[i] = 0; Fb[i] = 0; }
        if (hi == 0) {
            int ga = base + lm;      if (ga >= nAtoms) ga = nAtoms - 1;
            int gb = base + 32 + lm; if (gb >= nAtoms) gb = nAtoms - 1;
            Fa[0] = (short)f2bf(pos[ga * 3 + 0]);
            Fa[1] = (short)f2bf(pos[ga * 3 + 1]);
            Fa[2] = (short)f2bf(pos[ga * 3 + 2]);
            Fa[3] = (short)f2bf((float)anum[ga]);
            Fb[0] = (short)f2bf(pos[gb * 3 + 0]);
            Fb[1] = (short)f2bf(pos[gb * 3 + 1]);
            Fb[2] = (short)f2bf(pos[gb * 3 + 2]);
            Fb[3] = (short)f2bf((float)anum[gb]);
        }
        f32x16 acc0, acc1;
        #pragma unroll
        for (int r = 0; r < 16; ++r) {
            const float b = binL[Fw + (r & 3) + 8 * (r >> 2) + 4 * hi];
            acc0[r] = b; acc1[r] = b;
        }
        acc0 = __builtin_amdgcn_mfma_f32_32x32x16_bf16(Ain, Fa, acc0, 0, 0, 0);
        acc1 = __builtin_amdgcn_mfma_f32_32x32x16_bf16(Ain, Fb, acc1, 0, 0, 0);
        PACK_STORE(h1, acc0, acc1)
        __syncthreads();                 // h1 ready (also guards prev-tile h1 reads)

        // ---- layer 0: h1 -> h2 ----
        #pragma unroll
        for (int r = 0; r < 16; ++r) {
            const float b = bh0L[Fw + (r & 3) + 8 * (r >> 2) + 4 * hi];
            acc0[r] = b; acc1[r] = b;
        }
        MSTEP(A00, 0, h1)  MSTEP(A01, 1, h1)  MSTEP(A02, 2, h1)  MSTEP(A03, 3, h1)
        MSTEP(A04, 4, h1)  MSTEP(A05, 5, h1)  MSTEP(A06, 6, h1)  MSTEP(A07, 7, h1)
        PACK_STORE(h2, acc0, acc1)
        __syncthreads();                 // h2 ready (h1 reads complete)

        // ---- layer 1: h2 -> epilogue ----
        #pragma unroll
        for (int r = 0; r < 16; ++r) {
            const float b = bh1L[Fw + (r & 3) + 8 * (r >> 2) + 4 * hi];
            acc0[r] = b; acc1[r] = b;
        }
        MSTEP(A10, 0, h2)  MSTEP(A11, 1, h2)  MSTEP(A12, 2, h2)  MSTEP(A13, 3, h2)
        MSTEP(A14, 4, h2)  MSTEP(A15, 5, h2)  MSTEP(A16, 6, h2)  MSTEP(A17, 7, h2)

        const bool v0 = (base + lm)      < nAtoms;
        const bool v1 = (base + 32 + lm) < nAtoms;
        float e0 = 0.f, e1 = 0.f;
        #pragma unroll
        for (int r = 0; r < 16; ++r) {
            const int f = Fw + (r & 3) + 8 * (r >> 2) + 4 * hi;
            const float h3a = silu(acc0[r]);
            const float h3b = silu(acc1[r]);
            const float we = WeL[f];
            e0 = fmaf(h3a, we, e0);
            e1 = fmaf(h3b, we, e1);
            hsum[r] += (v0 ? h3a : 0.f) + (v1 ? h3b : 0.f);   // W_s folded after loop
        }
        e0 += __shfl_xor(e0, 32);
        e1 += __shfl_xor(e1, 32);
        const float ev = (lane < 32) ? e0 : e1;   // lane l <-> atom base+l
        ered[w * 64 + lane] = ev;
        __syncthreads();                 // ered ready (h2 reads complete)

        if (w == 0) {
            float e = ered[lane] + ered[64 + lane] + ered[128 + lane] + ered[192 + lane] + be;
            const int ga = base + lane;
            int key = (ga < nAtoms) ? batch[ga] : -1;
            if (key < 0) e = 0.f;
            #pragma unroll
            for (int d = 1; d < 64; d <<= 1) {
                const float eo = __shfl_down(e, d);
                const int   ko = __shfl_down(key, d);
                const bool valid = ((lane + d) < 64) && (ko == key);
                e += valid ? eo : 0.f;
            }
            const int kprev = __shfl_up(key, 1);
            const bool head = (lane == 0) || (kprev != key);
            if (head && key >= 0) atomicAdd(&out_energies[key], e);
        }
    }

    // ---- fold W_s once, wave-reduce, atomic ----
    float s0 = 0.f, s1 = 0.f, s2 = 0.f, s3 = 0.f, s4 = 0.f, s5 = 0.f;
    #pragma unroll
    for (int r = 0; r < 16; ++r) {
        const int f = Fw + (r & 3) + 8 * (r >> 2) + 4 * hi;
        const float h = hsum[r];
        s0 = fmaf(h, WsL[f][0], s0); s1 = fmaf(h, WsL[f][1], s1);
        s2 = fmaf(h, WsL[f][2], s2); s3 = fmaf(h, WsL[f][3], s3);
        s4 = fmaf(h, WsL[f][4], s4); s5 = fmaf(h, WsL[f][5], s5);
    }
    #pragma unroll
    for (int d = 1; d < 64; d <<= 1) {
        s0 += __shfl_xor(s0, d); s1 += __shfl_xor(s1, d); s2 += __shfl_xor(s2, d);
        s3 += __shfl_xor(s3, d); s4 += __shfl_xor(s4, d); s5 += __shfl_xor(s5, d);
    }
    if (lane == 0) {
        atomicAdd(&ws6[0], s0); atomicAdd(&ws6[1], s1); atomicAdd(&ws6[2], s2);
        atomicAdd(&ws6[3], s3); atomicAdd(&ws6[4], s4); atomicAdd(&ws6[5], s5);
    }
}

__global__ void stress_kernel(const float* __restrict__ ws6,
                              const float* __restrict__ b_s,
                              float* __restrict__ out_stress, float invN)
{
    const int c = threadIdx.x;
    if (c < 6) out_stress[c] = fmaf(ws6[c], invN, b_s[c]);
}

extern "C" void kernel_launch(void* const* d_in, const int* in_sizes, int n_in,
                              void* d_out, int out_size, void* d_ws, size_t ws_size,
                              hipStream_t stream) {
    const float* pos  = (const float*)d_in[0];
    const int*   anum = (const int*)d_in[1];
    const int*   batch= (const int*)d_in[2];
    const float* W_in = (const float*)d_in[3];
    const float* b_in = (const float*)d_in[4];
    const float* W_h  = (const float*)d_in[5];
    const float* b_h  = (const float*)d_in[6];
    const float* W_e  = (const float*)d_in[7];
    const float* b_e  = (const float*)d_in[8];
    const float* W_s  = (const float*)d_in[9];
    const float* b_s  = (const float*)d_in[10];

    float* out = (float*)d_out;
    const int nAtoms  = in_sizes[2];
    const int nStruct = out_size - 3 * nAtoms - 6;   // energies | forces | stress
    float* ws6 = (float*)d_ws;

    hipMemsetAsync(d_out, 0, (size_t)out_size * sizeof(float), stream);
    hipMemsetAsync(d_ws, 0, 32, stream);

    mlp_kernel<<<NBLOCKS, TPB, 0, stream>>>(pos, anum, batch, W_in, b_in, W_h, b_h,
                                            W_e, b_e, W_s, out, ws6, nAtoms);
    stress_kernel<<<1, 64, 0, stream>>>(ws6, b_s,
                                        out + (size_t)nStruct + 3 * (size_t)nAtoms,
                                        1.0f / (float)nAtoms);
}